// Round 4
// baseline (203.504 us; speedup 1.0000x reference)
//
#include <hip/hip_runtime.h>
#include <stdint.h>

#define B_ 4096
#define D_ 1024
#define TINV 10.0f
#define LOG2E 1.4426950408889634f
#define KE (TINV * LOG2E)
#define INV_BM1 (1.0f / 4095.0f)
#define SZ 131072   // 32 * B_  (one partial plane)

typedef __bf16 bf16x8 __attribute__((ext_vector_type(8)));
typedef float f32x4 __attribute__((ext_vector_type(4)));

__device__ __forceinline__ unsigned short f2bf(float x) {
  uint32_t b = __float_as_uint(x);
  b += 0x7FFF + ((b >> 16) & 1);   // RNE
  return (unsigned short)(b >> 16);
}

__device__ __forceinline__ void gload16(const void* g, void* l) {
  __builtin_amdgcn_global_load_lds(
      (const __attribute__((address_space(1))) uint32_t*)g,
      (__attribute__((address_space(3))) uint32_t*)l, 16, 0, 0);
}

// ---------------- K1: L2-normalize rows, emit bf16 ----------------
__global__ __launch_bounds__(256) void k_normalize(const float* __restrict__ zis,
                                                   const float* __restrict__ zjs,
                                                   unsigned short* __restrict__ Abf,
                                                   unsigned short* __restrict__ Bbf) {
  int r = blockIdx.x;
  const float* src;
  unsigned short* dst;
  if (r < B_) { src = zis + (size_t)r * D_; dst = Abf + (size_t)r * D_; }
  else        { src = zjs + (size_t)(r - B_) * D_; dst = Bbf + (size_t)(r - B_) * D_; }
  int t = threadIdx.x;
  float4 v = reinterpret_cast<const float4*>(src)[t];
  float ss = v.x*v.x + v.y*v.y + v.z*v.z + v.w*v.w;
  #pragma unroll
  for (int o = 32; o >= 1; o >>= 1) ss += __shfl_down(ss, o);
  __shared__ float red[4];
  if ((t & 63) == 0) red[t >> 6] = ss;
  __syncthreads();
  float sc = rsqrtf(red[0] + red[1] + red[2] + red[3]);
  ushort4 o4;
  o4.x = f2bf(v.x * sc); o4.y = f2bf(v.y * sc);
  o4.z = f2bf(v.z * sc); o4.w = f2bf(v.w * sc);
  reinterpret_cast<ushort4*>(dst)[t] = o4;
}

// ---------------- K2: GEMM + LDS-staged statistics epilogue ----------------
// No C store. S layout: [0]=rmax, [SZ]=rE, [2SZ]=rE2, [3SZ]=cmax, [4SZ]=cE,
// [5SZ]=cE2 partial planes (32 x B_), [6SZ]=diag (B_).
__global__ __launch_bounds__(256) void k_gemm(const unsigned short* __restrict__ A,
                                              const unsigned short* __restrict__ B,
                                              float* __restrict__ S) {
  __shared__ union {
    unsigned short u16[2][128 * 32];   // As / Bs staging (16 KB)
    float stat[32][132];               // epilogue scratch (16.9 KB, padded)
  } sm;
  __shared__ float cP[128][3];
  const int tid = threadIdx.x;
  const int wid = tid >> 6;
  const int lane = tid & 63;
  const int wr = wid >> 1, wc = wid & 1;
  const int by = blockIdx.y, bx = blockIdx.x;

  f32x4 acc[4][4] = {};

  const int lrow = lane >> 2;        // 0..15 within chunk
  const int lcol = (lane & 3) * 8;   // k offset (elements)
  const int frow = lane & 15;
  const int fcol = (lane >> 4) * 8;

  for (int k0 = 0; k0 < D_; k0 += 32) {
    #pragma unroll
    for (int i = 0; i < 2; ++i) {
      int chunk = i * 4 + wid;       // 0..7 ; 1KB (16 rows) each
      int r = chunk * 16 + lrow;     // 0..127
      gload16(A + (size_t)(by * 128 + r) * D_ + k0 + lcol, &sm.u16[0][chunk * 512]);
      gload16(B + (size_t)(bx * 128 + r) * D_ + k0 + lcol, &sm.u16[1][chunk * 512]);
    }
    __syncthreads();
    bf16x8 af[4], bfr[4];
    #pragma unroll
    for (int m = 0; m < 4; ++m)
      af[m] = *reinterpret_cast<const bf16x8*>(&sm.u16[0][(wr*64 + m*16 + frow) * 32 + fcol]);
    #pragma unroll
    for (int n = 0; n < 4; ++n)
      bfr[n] = *reinterpret_cast<const bf16x8*>(&sm.u16[1][(wc*64 + n*16 + frow) * 32 + fcol]);
    #pragma unroll
    for (int m = 0; m < 4; ++m)
      #pragma unroll
      for (int n = 0; n < 4; ++n)
        acc[m][n] = __builtin_amdgcn_mfma_f32_16x16x32_bf16(af[m], bfr[n], acc[m][n], 0, 0, 0);
    __syncthreads();
  }

  // --- diag extraction (C/D layout: row=(lane>>4)*4+q, col=lane&15) ---
  if (bx == by && wr == wc) {
    #pragma unroll
    for (int m = 0; m < 4; ++m)
      #pragma unroll
      for (int q = 0; q < 4; ++q)
        if ((lane & 15) == ((lane >> 4) * 4 + q))
          S[6 * SZ + by * 128 + wr * 64 + m * 16 + (lane & 15)] = acc[m][m][q];
  }

  // --- stats epilogue: 4 LDS-staged phases, 32 rows x 128 cols each ---
  const int rowt = tid >> 3;          // 0..31  (row within phase tile)
  const int colt = (tid & 7) * 16;    // 0..112 (col start, 16 wide)
  const int cc_  = tid & 127;         // owned column
  const int hh_  = tid >> 7;          // row-half for col stats
  float cmax = -3.4e38f, cE = 0.f, cE2 = 0.f;

  #pragma unroll
  for (int m = 0; m < 4; ++m) {
    __syncthreads();   // previous phase reads (or K-loop) done
    #pragma unroll
    for (int n = 0; n < 4; ++n)
      #pragma unroll
      for (int q = 0; q < 4; ++q)
        sm.stat[wr * 16 + (lane >> 4) * 4 + q][wc * 64 + n * 16 + (lane & 15)] = acc[m][n][q];
    __syncthreads();
    // row stats: 8 threads per row, 16 contiguous cols each
    float smax = -3.4e38f, sE = 0.f, sE2 = 0.f;
    #pragma unroll
    for (int k4 = 0; k4 < 4; ++k4) {
      float4 x = *reinterpret_cast<const float4*>(&sm.stat[rowt][colt + k4 * 4]);
      float e0 = exp2f(x.x * KE), e1 = exp2f(x.y * KE);
      float e2 = exp2f(x.z * KE), e3 = exp2f(x.w * KE);
      smax = fmaxf(fmaxf(smax, fmaxf(x.x, x.y)), fmaxf(x.z, x.w));
      sE  += (e0 + e1) + (e2 + e3);
      sE2 += (e0 * x.x + e1 * x.y) + (e2 * x.z + e3 * x.w);
    }
    #pragma unroll
    for (int o = 1; o <= 4; o <<= 1) {
      smax = fmaxf(smax, __shfl_xor(smax, o));
      sE  += __shfl_xor(sE, o);
      sE2 += __shfl_xor(sE2, o);
    }
    if ((tid & 7) == 0) {
      int tr = (rowt >> 4) * 64 + m * 16 + (rowt & 15);   // row within 128-tile
      size_t o = (size_t)bx * B_ + by * 128 + tr;
      S[o] = smax; S[SZ + o] = sE; S[2 * SZ + o] = sE2;
    }
    // col stats: 2 threads per col, 16 rows each; accumulate across phases
    #pragma unroll
    for (int k = 0; k < 16; ++k) {
      float x = sm.stat[hh_ * 16 + k][cc_];
      float e = exp2f(x * KE);
      cmax = fmaxf(cmax, x); cE += e; cE2 += e * x;
    }
  }
  __syncthreads();
  if (tid >= 128) { cP[cc_][0] = cmax; cP[cc_][1] = cE; cP[cc_][2] = cE2; }
  __syncthreads();
  if (tid < 128) {
    cmax = fmaxf(cmax, cP[tid][0]); cE += cP[tid][1]; cE2 += cP[tid][2];
    size_t o = (size_t)by * B_ + bx * 128 + tid;
    S[3 * SZ + o] = cmax; S[4 * SZ + o] = cE; S[5 * SZ + o] = cE2;
  }
}

// ---------------- K3: reduce partials -> per-index losses -> block partial sums ----
__global__ __launch_bounds__(256) void k_reduce(
    const float* __restrict__ S,
    const float* __restrict__ bI, const float* __restrict__ bT,
    const float* __restrict__ sI, const float* __restrict__ sT,
    const int* __restrict__ ids, float* __restrict__ partial) {
  const int t = threadIdx.x;
  const int i = blockIdx.x * 256 + t;
  const float dg = S[6 * SZ + i];
  const int id = ids[i];
  const float ed = exp2f(dg * KE);

  // image (row) side
  float mx = -3.4e38f, E = 0.f, E2 = 0.f;
  for (int p = 0; p < 32; ++p) {
    size_t o = (size_t)p * B_ + i;
    mx = fmaxf(mx, S[o]); E += S[SZ + o]; E2 += S[2 * SZ + o];
  }
  float oldb = bI[id];
  float newb = fmaxf((mx - dg) * TINV, oldb);
  float sc = exp2f(-(dg * TINV + newb) * LOG2E);
  float S1 = (E - ed) * sc;
  float S2 = (E2 - dg * E) * sc;
  float g = S1 * INV_BM1;
  float sn = 0.2f * sI[id] * exp2f((oldb - newb) * LOG2E) + 0.8f * g;
  float li = S2 / fmaxf(sn, 1e-14f) * INV_BM1;

  // text (col) side
  mx = -3.4e38f; E = 0.f; E2 = 0.f;
  for (int p = 0; p < 32; ++p) {
    size_t o = (size_t)p * B_ + i;
    mx = fmaxf(mx, S[3 * SZ + o]); E += S[4 * SZ + o]; E2 += S[5 * SZ + o];
  }
  oldb = bT[id];
  newb = fmaxf((mx - dg) * TINV, oldb);
  sc = exp2f(-(dg * TINV + newb) * LOG2E);
  S1 = (E - ed) * sc;
  S2 = (E2 - dg * E) * sc;
  g = S1 * INV_BM1;
  sn = 0.2f * sT[id] * exp2f((oldb - newb) * LOG2E) + 0.8f * g;
  float lt = S2 / fmaxf(sn, 1e-14f) * INV_BM1;

  float v = (0.5f * li + 0.5f * lt) * (1.0f / (float)B_);
  #pragma unroll
  for (int o = 32; o >= 1; o >>= 1) v += __shfl_down(v, o);
  __shared__ float red[4];
  if ((t & 63) == 0) red[t >> 6] = v;
  __syncthreads();
  if (t == 0) partial[blockIdx.x] = red[0] + red[1] + red[2] + red[3];
}

__global__ void k_final2(const float* __restrict__ partial, float* __restrict__ out) {
  float v = (threadIdx.x < 16) ? partial[threadIdx.x] : 0.f;
  #pragma unroll
  for (int o = 32; o >= 1; o >>= 1) v += __shfl_down(v, o);
  if (threadIdx.x == 0) out[0] = v;
}

extern "C" void kernel_launch(void* const* d_in, const int* in_sizes, int n_in,
                              void* d_out, int out_size, void* d_ws, size_t ws_size,
                              hipStream_t stream) {
  const float* zis = (const float*)d_in[0];
  const float* zjs = (const float*)d_in[1];
  const float* s_I = (const float*)d_in[2];
  const float* s_T = (const float*)d_in[3];
  const float* b_I = (const float*)d_in[4];
  const float* b_T = (const float*)d_in[5];
  const int*   ids = (const int*)d_in[6];

  char* ws = (char*)d_ws;
  size_t off = 0;
  auto alloc = [&](size_t bytes) -> void* {
    void* p = ws + off;
    off = (off + bytes + 255) & ~(size_t)255;
    return p;
  };
  unsigned short* Abf = (unsigned short*)alloc((size_t)B_ * D_ * 2);   // 8 MB
  unsigned short* Bbf = (unsigned short*)alloc((size_t)B_ * D_ * 2);   // 8 MB
  float* S      = (float*)alloc((size_t)(6 * SZ + B_) * 4);            // ~3.1 MB
  float* partial = (float*)alloc(16 * 4);

  k_normalize<<<2 * B_, 256, 0, stream>>>(zis, zjs, Abf, Bbf);
  k_gemm<<<dim3(32, 32), 256, 0, stream>>>(Abf, Bbf, S);
  k_reduce<<<16, 256, 0, stream>>>(S, b_I, b_T, s_I, s_T, ids, partial);
  k_final2<<<1, 64, 0, stream>>>(partial, (float*)d_out);
}

// Round 5
// 98.498 us; speedup vs baseline: 2.0661x; 2.0661x over previous
//
#include <hip/hip_runtime.h>
#include <stdint.h>

#define B_ 4096
#define D_ 1024
#define TINV 10.0f
#define LOG2E 1.4426950408889634f
#define KE (TINV * LOG2E)
#define INV_BM1 (1.0f / 4095.0f)

typedef __bf16 bf16x8 __attribute__((ext_vector_type(8)));
typedef float f32x4 __attribute__((ext_vector_type(4)));

__device__ __forceinline__ unsigned short f2bf(float x) {
  uint32_t b = __float_as_uint(x);
  b += 0x7FFF + ((b >> 16) & 1);   // RNE
  return (unsigned short)(b >> 16);
}
__device__ __forceinline__ float bf2f(unsigned short u) {
  return __uint_as_float(((uint32_t)u) << 16);
}

__device__ __forceinline__ void gload16(const void* g, void* l) {
  __builtin_amdgcn_global_load_lds(
      (const __attribute__((address_space(1))) uint32_t*)g,
      (__attribute__((address_space(3))) uint32_t*)l, 16, 0, 0);
}

// ---------------- K1: L2-normalize rows, emit bf16 ----------------
__global__ __launch_bounds__(256) void k_normalize(const float* __restrict__ zis,
                                                   const float* __restrict__ zjs,
                                                   unsigned short* __restrict__ Abf,
                                                   unsigned short* __restrict__ Bbf) {
  int r = blockIdx.x;
  const float* src;
  unsigned short* dst;
  if (r < B_) { src = zis + (size_t)r * D_; dst = Abf + (size_t)r * D_; }
  else        { src = zjs + (size_t)(r - B_) * D_; dst = Bbf + (size_t)(r - B_) * D_; }
  int t = threadIdx.x;
  float4 v = reinterpret_cast<const float4*>(src)[t];
  float ss = v.x*v.x + v.y*v.y + v.z*v.z + v.w*v.w;
  #pragma unroll
  for (int o = 32; o >= 1; o >>= 1) ss += __shfl_down(ss, o);
  __shared__ float red[4];
  if ((t & 63) == 0) red[t >> 6] = ss;
  __syncthreads();
  float sc = rsqrtf(red[0] + red[1] + red[2] + red[3]);
  ushort4 o4;
  o4.x = f2bf(v.x * sc); o4.y = f2bf(v.y * sc);
  o4.z = f2bf(v.z * sc); o4.w = f2bf(v.w * sc);
  reinterpret_cast<ushort4*>(dst)[t] = o4;
}

// ---------------- K2: sim = A * B^T (bf16 MFMA, R1-proven structure, bf16 store) ----
__global__ __launch_bounds__(256) void k_gemm(const unsigned short* __restrict__ A,
                                              const unsigned short* __restrict__ B,
                                              unsigned short* __restrict__ C) {
  __shared__ unsigned short As[128 * 32];
  __shared__ unsigned short Bs[128 * 32];
  const int tid = threadIdx.x;
  const int wid = tid >> 6;
  const int lane = tid & 63;
  const int wr = wid >> 1, wc = wid & 1;
  const int by = blockIdx.y, bx = blockIdx.x;

  f32x4 acc[4][4] = {};

  const int lrow = lane >> 2;        // 0..15 within chunk
  const int lcol = (lane & 3) * 8;   // k offset (elements)
  const int frow = lane & 15;
  const int fcol = (lane >> 4) * 8;

  for (int k0 = 0; k0 < D_; k0 += 32) {
    #pragma unroll
    for (int i = 0; i < 2; ++i) {
      int chunk = i * 4 + wid;       // 0..7 ; 1KB (16 rows) each
      int r = chunk * 16 + lrow;     // 0..127
      gload16(A + (size_t)(by * 128 + r) * D_ + k0 + lcol, &As[chunk * 512]);
      gload16(B + (size_t)(bx * 128 + r) * D_ + k0 + lcol, &Bs[chunk * 512]);
    }
    __syncthreads();
    bf16x8 af[4], bfr[4];
    #pragma unroll
    for (int m = 0; m < 4; ++m)
      af[m] = *reinterpret_cast<const bf16x8*>(&As[(wr*64 + m*16 + frow) * 32 + fcol]);
    #pragma unroll
    for (int n = 0; n < 4; ++n)
      bfr[n] = *reinterpret_cast<const bf16x8*>(&Bs[(wc*64 + n*16 + frow) * 32 + fcol]);
    #pragma unroll
    for (int m = 0; m < 4; ++m)
      #pragma unroll
      for (int n = 0; n < 4; ++n)
        acc[m][n] = __builtin_amdgcn_mfma_f32_16x16x32_bf16(af[m], bfr[n], acc[m][n], 0, 0, 0);
    __syncthreads();
  }

  const int crow0 = by * 128 + wr * 64;
  const int ccol0 = bx * 128 + wc * 64;
  #pragma unroll
  for (int m = 0; m < 4; ++m)
    #pragma unroll
    for (int n = 0; n < 4; ++n)
      #pragma unroll
      for (int q = 0; q < 4; ++q) {
        int rr = crow0 + m*16 + (lane >> 4)*4 + q;   // row = (lane>>4)*4+reg
        int cc = ccol0 + n*16 + (lane & 15);         // col = lane&15
        C[(size_t)rr * B_ + cc] = f2bf(acc[m][n][q]);
      }
}

// ---------------- K3: fused single-read pass over bf16 sim ----------------
// 256 blocks x 16 rows. Row losses finalized in-kernel; col {max,E,E2}
// partials kept in registers (16 cols/thread) and written once per block.
__global__ __launch_bounds__(256) void k_fused(const unsigned short* __restrict__ sim,
    const float* __restrict__ bI, const float* __restrict__ sI,
    const int* __restrict__ ids,
    float* __restrict__ LI, float* __restrict__ cmax_p,
    float* __restrict__ cE_p, float* __restrict__ cE2_p) {
  const int i0 = blockIdx.x * 16;
  const int t = threadIdx.x;
  const int w = t >> 6, lane = t & 63;
  __shared__ float rowPart[16][4][3];

  float cmax[16], cE[16], cE2[16];
  #pragma unroll
  for (int k = 0; k < 16; ++k) { cmax[k] = -3.4e38f; cE[k] = 0.f; cE2[k] = 0.f; }

  for (int r = 0; r < 16; ++r) {
    const unsigned short* sp = sim + (size_t)(i0 + r) * B_ + t * 16;
    uint4 u0 = *reinterpret_cast<const uint4*>(sp);
    uint4 u1 = *reinterpret_cast<const uint4*>(sp + 8);
    float x[16];
    x[0]  = __uint_as_float(u0.x << 16); x[1]  = __uint_as_float(u0.x & 0xffff0000u);
    x[2]  = __uint_as_float(u0.y << 16); x[3]  = __uint_as_float(u0.y & 0xffff0000u);
    x[4]  = __uint_as_float(u0.z << 16); x[5]  = __uint_as_float(u0.z & 0xffff0000u);
    x[6]  = __uint_as_float(u0.w << 16); x[7]  = __uint_as_float(u0.w & 0xffff0000u);
    x[8]  = __uint_as_float(u1.x << 16); x[9]  = __uint_as_float(u1.x & 0xffff0000u);
    x[10] = __uint_as_float(u1.y << 16); x[11] = __uint_as_float(u1.y & 0xffff0000u);
    x[12] = __uint_as_float(u1.z << 16); x[13] = __uint_as_float(u1.z & 0xffff0000u);
    x[14] = __uint_as_float(u1.w << 16); x[15] = __uint_as_float(u1.w & 0xffff0000u);
    float rmx = -3.4e38f, rE = 0.f, rE2 = 0.f;
    #pragma unroll
    for (int k = 0; k < 16; ++k) {
      float e = exp2f(x[k] * KE);
      rmx = fmaxf(rmx, x[k]);
      rE += e;
      rE2 = fmaf(e, x[k], rE2);
      cmax[k] = fmaxf(cmax[k], x[k]);
      cE[k] += e;
      cE2[k] = fmaf(e, x[k], cE2[k]);
    }
    #pragma unroll
    for (int o = 32; o >= 1; o >>= 1) {
      rmx = fmaxf(rmx, __shfl_down(rmx, o));
      rE += __shfl_down(rE, o);
      rE2 += __shfl_down(rE2, o);
    }
    if (lane == 0) { rowPart[r][w][0] = rmx; rowPart[r][w][1] = rE; rowPart[r][w][2] = rE2; }
  }
  __syncthreads();
  if (t < 16) {
    int i = i0 + t;
    float mx = fmaxf(fmaxf(rowPart[t][0][0], rowPart[t][1][0]),
                     fmaxf(rowPart[t][2][0], rowPart[t][3][0]));
    float E  = (rowPart[t][0][1] + rowPart[t][1][1]) + (rowPart[t][2][1] + rowPart[t][3][1]);
    float E2 = (rowPart[t][0][2] + rowPart[t][1][2]) + (rowPart[t][2][2] + rowPart[t][3][2]);
    float dg = bf2f(sim[(size_t)i * (B_ + 1)]);
    float ed = exp2f(dg * KE);
    int id = ids[i];
    float oldb = bI[id];
    float newb = fmaxf((mx - dg) * TINV, oldb);
    float sc = exp2f(-(dg * TINV + newb) * LOG2E);
    float S1 = (E - ed) * sc;
    float S2 = (E2 - dg * E) * sc;
    float g = S1 * INV_BM1;
    float sn = 0.2f * sI[id] * exp2f((oldb - newb) * LOG2E) + 0.8f * g;
    LI[i] = S2 / fmaxf(sn, 1e-14f) * INV_BM1;
  }
  size_t base = (size_t)blockIdx.x * B_ + t * 16;
  #pragma unroll
  for (int k = 0; k < 16; ++k) {
    cmax_p[base + k] = cmax[k];
    cE_p[base + k]   = cE[k];
    cE2_p[base + k]  = cE2[k];
  }
}

// ---------------- K4: column reduce (512 blocks, 32 threads/col) ----------------
__global__ __launch_bounds__(256) void k_colred(const unsigned short* __restrict__ sim,
    const float* __restrict__ cmax_p, const float* __restrict__ cE_p,
    const float* __restrict__ cE2_p,
    const float* __restrict__ bT, const float* __restrict__ sT,
    const int* __restrict__ ids, const float* __restrict__ LI,
    float* __restrict__ partial) {
  const int t = threadIdx.x;
  const int cidx = t >> 5;          // 0..7 (col within block)
  const int sub = t & 31;
  const int j = blockIdx.x * 8 + cidx;
  float mx = -3.4e38f, E = 0.f, E2 = 0.f;
  #pragma unroll
  for (int k = 0; k < 8; ++k) {
    size_t o = (size_t)(sub + 32 * k) * B_ + j;
    mx = fmaxf(mx, cmax_p[o]);
    E += cE_p[o];
    E2 += cE2_p[o];
  }
  #pragma unroll
  for (int o = 16; o >= 1; o >>= 1) {
    mx = fmaxf(mx, __shfl_down(mx, o, 32));
    E += __shfl_down(E, o, 32);
    E2 += __shfl_down(E2, o, 32);
  }
  __shared__ float red[8];
  if (sub == 0) {
    float dg = bf2f(sim[(size_t)j * (B_ + 1)]);
    float ed = exp2f(dg * KE);
    int id = ids[j];
    float oldb = bT[id];
    float newb = fmaxf((mx - dg) * TINV, oldb);
    float sc = exp2f(-(dg * TINV + newb) * LOG2E);
    float S1 = (E - ed) * sc;
    float S2 = (E2 - dg * E) * sc;
    float g = S1 * INV_BM1;
    float sn = 0.2f * sT[id] * exp2f((oldb - newb) * LOG2E) + 0.8f * g;
    float lt = S2 / fmaxf(sn, 1e-14f) * INV_BM1;
    red[cidx] = (0.5f * LI[j] + 0.5f * lt) * (1.0f / (float)B_);
  }
  __syncthreads();
  if (t == 0) {
    float s = 0.f;
    #pragma unroll
    for (int k = 0; k < 8; ++k) s += red[k];
    partial[blockIdx.x] = s;
  }
}

// ---------------- K5: final reduce over 512 partials ----------------
__global__ void k_final2(const float* __restrict__ partial, float* __restrict__ out) {
  int t = threadIdx.x;
  float v = partial[t];
  #pragma unroll
  for (int o = 32; o >= 1; o >>= 1) v += __shfl_down(v, o);
  __shared__ float red[8];
  if ((t & 63) == 0) red[t >> 6] = v;
  __syncthreads();
  if (t == 0) {
    float s = 0.f;
    #pragma unroll
    for (int k = 0; k < 8; ++k) s += red[k];
    out[0] = s;
  }
}

extern "C" void kernel_launch(void* const* d_in, const int* in_sizes, int n_in,
                              void* d_out, int out_size, void* d_ws, size_t ws_size,
                              hipStream_t stream) {
  const float* zis = (const float*)d_in[0];
  const float* zjs = (const float*)d_in[1];
  const float* s_I = (const float*)d_in[2];
  const float* s_T = (const float*)d_in[3];
  const float* b_I = (const float*)d_in[4];
  const float* b_T = (const float*)d_in[5];
  const int*   ids = (const int*)d_in[6];

  char* ws = (char*)d_ws;
  size_t off = 0;
  auto alloc = [&](size_t bytes) -> void* {
    void* p = ws + off;
    off = (off + bytes + 255) & ~(size_t)255;
    return p;
  };
  unsigned short* Abf = (unsigned short*)alloc((size_t)B_ * D_ * 2);   // 8 MB
  unsigned short* Bbf = (unsigned short*)alloc((size_t)B_ * D_ * 2);   // 8 MB
  unsigned short* sim = (unsigned short*)alloc((size_t)B_ * B_ * 2);   // 32 MB
  float* cmax_p = (float*)alloc((size_t)256 * B_ * 4);                 // 4 MB each
  float* cE_p   = (float*)alloc((size_t)256 * B_ * 4);
  float* cE2_p  = (float*)alloc((size_t)256 * B_ * 4);
  float* LI     = (float*)alloc(B_ * 4);
  float* partial = (float*)alloc(512 * 4);

  k_normalize<<<2 * B_, 256, 0, stream>>>(zis, zjs, Abf, Bbf);
  k_gemm<<<dim3(32, 32), 256, 0, stream>>>(Abf, Bbf, sim);
  k_fused<<<256, 256, 0, stream>>>(sim, b_I, s_I, ids, LI, cmax_p, cE_p, cE2_p);
  k_colred<<<512, 256, 0, stream>>>(sim, cmax_p, cE_p, cE2_p, b_T, s_T, ids, LI, partial);
  k_final2<<<1, 512, 0, stream>>>(partial, (float*)d_out);
}

// Round 6
// 91.357 us; speedup vs baseline: 2.2276x; 1.0782x over previous
//
#include <hip/hip_runtime.h>
#include <stdint.h>

#define B_ 4096
#define D_ 1024
#define NT 16            // K tiles (1024 / 64)
#define TINV 10.0f
#define LOG2E 1.4426950408889634f
#define KE (TINV * LOG2E)
#define INV_BM1 (1.0f / 4095.0f)

typedef __bf16 bf16x8 __attribute__((ext_vector_type(8)));
typedef float f32x4 __attribute__((ext_vector_type(4)));

__device__ __forceinline__ unsigned short f2bf(float x) {
  uint32_t b = __float_as_uint(x);
  b += 0x7FFF + ((b >> 16) & 1);   // RNE
  return (unsigned short)(b >> 16);
}
__device__ __forceinline__ float bf2f(unsigned short u) {
  return __uint_as_float(((uint32_t)u) << 16);
}

__device__ __forceinline__ void gload16(const void* g, void* l) {
  __builtin_amdgcn_global_load_lds(
      (const __attribute__((address_space(1))) uint32_t*)g,
      (__attribute__((address_space(3))) uint32_t*)l, 16, 0, 0);
}

// ---------------- K1: L2-normalize rows, emit bf16 ----------------
__global__ __launch_bounds__(256) void k_normalize(const float* __restrict__ zis,
                                                   const float* __restrict__ zjs,
                                                   unsigned short* __restrict__ Abf,
                                                   unsigned short* __restrict__ Bbf) {
  int r = blockIdx.x;
  const float* src;
  unsigned short* dst;
  if (r < B_) { src = zis + (size_t)r * D_; dst = Abf + (size_t)r * D_; }
  else        { src = zjs + (size_t)(r - B_) * D_; dst = Bbf + (size_t)(r - B_) * D_; }
  int t = threadIdx.x;
  float4 v = reinterpret_cast<const float4*>(src)[t];
  float ss = v.x*v.x + v.y*v.y + v.z*v.z + v.w*v.w;
  #pragma unroll
  for (int o = 32; o >= 1; o >>= 1) ss += __shfl_down(ss, o);
  __shared__ float red[4];
  if ((t & 63) == 0) red[t >> 6] = ss;
  __syncthreads();
  float sc = rsqrtf(red[0] + red[1] + red[2] + red[3]);
  ushort4 o4;
  o4.x = f2bf(v.x * sc); o4.y = f2bf(v.y * sc);
  o4.z = f2bf(v.z * sc); o4.w = f2bf(v.w * sc);
  reinterpret_cast<ushort4*>(dst)[t] = o4;
}

// ---------------- K2: 256x256 8-phase GEMM (T2+T3+T4+T5), bf16 C + f32 diag ----
#define LDA(MH)                                                              \
  { _Pragma("unroll") for (int m4_ = 0; m4_ < 4; ++m4_) {                    \
      const unsigned short* p_ = &Abase[((MH)*64 + m4_*16 + fr) * 64];       \
      a[m4_][0] = *reinterpret_cast<const bf16x8*>(&p_[ce0]);                \
      a[m4_][1] = *reinterpret_cast<const bf16x8*>(&p_[ce1]); } }

#define LDB(NH)                                                              \
  { _Pragma("unroll") for (int n2_ = 0; n2_ < 2; ++n2_) {                    \
      const unsigned short* p_ = &Bbase[(bn_off + ((NH)*2+n2_)*16 + fr) * 64]; \
      b[(NH)*2+n2_][0] = *reinterpret_cast<const bf16x8*>(&p_[ce0]);         \
      b[(NH)*2+n2_][1] = *reinterpret_cast<const bf16x8*>(&p_[ce1]); } }

#define MFMAQ(MH, NH)                                                        \
  { _Pragma("unroll") for (int m4_ = 0; m4_ < 4; ++m4_) {                    \
      _Pragma("unroll") for (int n2_ = 0; n2_ < 2; ++n2_) {                  \
        acc[(MH)*4+m4_][(NH)*2+n2_] = __builtin_amdgcn_mfma_f32_16x16x32_bf16( \
            a[m4_][0], b[(NH)*2+n2_][0], acc[(MH)*4+m4_][(NH)*2+n2_], 0,0,0);  \
        acc[(MH)*4+m4_][(NH)*2+n2_] = __builtin_amdgcn_mfma_f32_16x16x32_bf16( \
            a[m4_][1], b[(NH)*2+n2_][1], acc[(MH)*4+m4_][(NH)*2+n2_], 0,0,0); } } }

#define STAGE_A(T, H)                                                        \
  { const unsigned short* g_ = Ag + (size_t)((H)*128)*D_ + (T)*64;           \
    gload16(g_ + so0, &lds[(T)&1][0][H][q0*512]);                            \
    gload16(g_ + so1, &lds[(T)&1][0][H][q1*512]); }

#define STAGE_B(T, H)                                                        \
  { const unsigned short* g_ = Bg + (size_t)((H)*128)*D_ + (T)*64;           \
    gload16(g_ + so0, &lds[(T)&1][1][H][q0*512]);                            \
    gload16(g_ + so1, &lds[(T)&1][1][H][q1*512]); }

#define SYNC_PRE                                                             \
  __builtin_amdgcn_s_barrier();                                              \
  asm volatile("s_waitcnt lgkmcnt(0)" ::: "memory");                         \
  __builtin_amdgcn_sched_barrier(0);                                         \
  __builtin_amdgcn_s_setprio(1);

#define SYNC_POST                                                            \
  __builtin_amdgcn_s_setprio(0);                                             \
  __builtin_amdgcn_sched_barrier(0);                                         \
  __builtin_amdgcn_s_barrier();

__global__ __launch_bounds__(512, 2) void k_gemm(const unsigned short* __restrict__ A,
                                                 const unsigned short* __restrict__ B,
                                                 unsigned short* __restrict__ C,
                                                 float* __restrict__ diagp) {
  __shared__ unsigned short lds[2][2][2][8192];   // [slot][A/B][half][128*64] = 128 KB
  const int tid = threadIdx.x;
  const int wid = tid >> 6;
  const int lane = tid & 63;
  const int wm = wid >> 2;          // 0..1
  const int wn = wid & 3;           // 0..3
  const int bRow = blockIdx.y * 256;
  const int bCol = blockIdx.x * 256;
  const unsigned short* Ag = A + (size_t)bRow * D_;
  const unsigned short* Bg = B + (size_t)bCol * D_;

  // staging lane geometry (2 gload16 per wave per half-tile; q0/q1 = instr ids)
  const int q0 = wid * 2, q1 = q0 + 1;
  const int srow = q0 * 8 + (lane >> 3);                       // row in half-tile
  const int scol = ((lane & 7) * 8) ^ (((lane >> 5) & 1) << 4); // pre-swizzled src col
  const size_t so0 = (size_t)srow * D_ + scol;
  const size_t so1 = (size_t)(srow + 8) * D_ + (scol ^ 32);

  // fragment-read geometry (swizzled: col-byte bits5,6 ^= row bits2,3)
  const int fr = lane & 15;
  const int sx = (((lane >> 2) & 1) << 4) | (((lane >> 3) & 1) << 5);
  const int ce0 = ((lane >> 4) * 8) ^ sx;
  const int ce1 = (((lane >> 4) * 8) + 32) ^ sx;
  const int bn_off = (wn & 1) * 64;

  f32x4 acc[8][4] = {};

  // ---- prologue: tile0 {A0,A1,B0,B1}, tile1 {B0,A0}; then drain tile0 ----
  STAGE_A(0, 0); STAGE_A(0, 1); STAGE_B(0, 0); STAGE_B(0, 1);
  STAGE_B(1, 0); STAGE_A(1, 0);
  asm volatile("s_waitcnt vmcnt(4)" ::: "memory");
  __builtin_amdgcn_sched_barrier(0);
  __builtin_amdgcn_s_barrier();

  for (int t = 0; t < NT; ++t) {
    const int s = t & 1;
    const unsigned short* Abase = &lds[s][0][wm][0];
    const unsigned short* Bbase = &lds[s][1][wn >> 1][0];
    bf16x8 a[4][2], b[4][2];

    // P1: quadrant (mh0, nh0); stage (t+1).B1
    LDA(0); LDB(0);
    if (t + 1 < NT) { STAGE_B(t + 1, 1); }
    SYNC_PRE; MFMAQ(0, 0); SYNC_POST;

    // P2: (mh0, nh1); stage (t+1).A1
    LDB(1);
    if (t + 1 < NT) { STAGE_A(t + 1, 1); }
    SYNC_PRE; MFMAQ(0, 1); SYNC_POST;

    // P3: (mh1, nh0); stage (t+2).B0  (B-halves of slot s freed after P2)
    LDA(1);
    if (t + 2 < NT) { __builtin_amdgcn_sched_barrier(0); STAGE_B(t + 2, 0); }
    SYNC_PRE; MFMAQ(1, 0); SYNC_POST;

    // P4: (mh1, nh1); stage (t+2).A0  (A-halves freed after P3)
    if (t + 2 < NT) { __builtin_amdgcn_sched_barrier(0); STAGE_A(t + 2, 0); }
    __builtin_amdgcn_s_setprio(1);
    MFMAQ(1, 1);
    __builtin_amdgcn_s_setprio(0);
    if (t < NT - 2) {
      asm volatile("s_waitcnt vmcnt(4)" ::: "memory");
    } else if (t == NT - 2) {
      asm volatile("s_waitcnt vmcnt(0)" ::: "memory");
    }
    __builtin_amdgcn_sched_barrier(0);
    if (t < NT - 1) __builtin_amdgcn_s_barrier();
  }

  // ---- epilogue: diag (f32) + packed bf16x2 C store ----
  const int fr4 = (lane >> 4) * 4;
  #pragma unroll
  for (int m = 0; m < 8; ++m)
    #pragma unroll
    for (int n = 0; n < 4; ++n)
      #pragma unroll
      for (int q = 0; q < 4; ++q) {
        float v = acc[m][n][q];
        int rg = bRow + wm * 128 + m * 16 + fr4 + q;
        int cg = bCol + wn * 64 + n * 16 + fr;
        if (rg == cg) diagp[rg] = v;
        float p = __shfl_xor(v, 1);
        if (!(lane & 1)) {
          uint32_t u = (uint32_t)f2bf(v) | ((uint32_t)f2bf(p) << 16);
          *reinterpret_cast<uint32_t*>(&C[(size_t)rg * B_ + cg]) = u;
        }
      }
}

// ---------------- K3: fused single-read pass over bf16 sim ----------------
__global__ __launch_bounds__(256) void k_fused(const unsigned short* __restrict__ sim,
    const float* __restrict__ diag,
    const float* __restrict__ bI, const float* __restrict__ sI,
    const int* __restrict__ ids,
    float* __restrict__ LI, float* __restrict__ cmax_p,
    float* __restrict__ cE_p, float* __restrict__ cE2_p) {
  const int i0 = blockIdx.x * 16;
  const int t = threadIdx.x;
  const int w = t >> 6, lane = t & 63;
  __shared__ float rowPart[16][4][3];

  float cmax[16], cE[16], cE2[16];
  #pragma unroll
  for (int k = 0; k < 16; ++k) { cmax[k] = -3.4e38f; cE[k] = 0.f; cE2[k] = 0.f; }

  for (int r = 0; r < 16; ++r) {
    const unsigned short* sp = sim + (size_t)(i0 + r) * B_ + t * 16;
    uint4 u0 = *reinterpret_cast<const uint4*>(sp);
    uint4 u1 = *reinterpret_cast<const uint4*>(sp + 8);
    float x[16];
    x[0]  = __uint_as_float(u0.x << 16); x[1]  = __uint_as_float(u0.x & 0xffff0000u);
    x[2]  = __uint_as_float(u0.y << 16); x[3]  = __uint_as_float(u0.y & 0xffff0000u);
    x[4]  = __uint_as_float(u0.z << 16); x[5]  = __uint_as_float(u0.z & 0xffff0000u);
    x[6]  = __uint_as_float(u0.w << 16); x[7]  = __uint_as_float(u0.w & 0xffff0000u);
    x[8]  = __uint_as_float(u1.x << 16); x[9]  = __uint_as_float(u1.x & 0xffff0000u);
    x[10] = __uint_as_float(u1.y << 16); x[11] = __uint_as_float(u1.y & 0xffff0000u);
    x[12] = __uint_as_float(u1.z << 16); x[13] = __uint_as_float(u1.z & 0xffff0000u);
    x[14] = __uint_as_float(u1.w << 16); x[15] = __uint_as_float(u1.w & 0xffff0000u);
    float rmx = -3.4e38f, rE = 0.f, rE2 = 0.f;
    #pragma unroll
    for (int k = 0; k < 16; ++k) {
      float e = exp2f(x[k] * KE);
      rmx = fmaxf(rmx, x[k]);
      rE += e;
      rE2 = fmaf(e, x[k], rE2);
      cmax[k] = fmaxf(cmax[k], x[k]);
      cE[k] += e;
      cE2[k] = fmaf(e, x[k], cE2[k]);
    }
    #pragma unroll
    for (int o = 32; o >= 1; o >>= 1) {
      rmx = fmaxf(rmx, __shfl_down(rmx, o));
      rE += __shfl_down(rE, o);
      rE2 += __shfl_down(rE2, o);
    }
    if (lane == 0) { rowPart[r][w][0] = rmx; rowPart[r][w][1] = rE; rowPart[r][w][2] = rE2; }
  }
  __syncthreads();
  if (t < 16) {
    int i = i0 + t;
    float mx = fmaxf(fmaxf(rowPart[t][0][0], rowPart[t][1][0]),
                     fmaxf(rowPart[t][2][0], rowPart[t][3][0]));
    float E  = (rowPart[t][0][1] + rowPart[t][1][1]) + (rowPart[t][2][1] + rowPart[t][3][1]);
    float E2 = (rowPart[t][0][2] + rowPart[t][1][2]) + (rowPart[t][2][2] + rowPart[t][3][2]);
    float dg = diag[i];
    float ed = exp2f(dg * KE);
    int id = ids[i];
    float oldb = bI[id];
    float newb = fmaxf((mx - dg) * TINV, oldb);
    float sc = exp2f(-(dg * TINV + newb) * LOG2E);
    float S1 = (E - ed) * sc;
    float S2 = (E2 - dg * E) * sc;
    float g = S1 * INV_BM1;
    float sn = 0.2f * sI[id] * exp2f((oldb - newb) * LOG2E) + 0.8f * g;
    LI[i] = S2 / fmaxf(sn, 1e-14f) * INV_BM1;
  }
  size_t base = (size_t)blockIdx.x * B_ + t * 16;
  #pragma unroll
  for (int k = 0; k < 16; ++k) {
    cmax_p[base + k] = cmax[k];
    cE_p[base + k]   = cE[k];
    cE2_p[base + k]  = cE2[k];
  }
}

// ---------------- K4: column reduce (512 blocks, 32 threads/col) ----------------
__global__ __launch_bounds__(256) void k_colred(
    const float* __restrict__ diag,
    const float* __restrict__ cmax_p, const float* __restrict__ cE_p,
    const float* __restrict__ cE2_p,
    const float* __restrict__ bT, const float* __restrict__ sT,
    const int* __restrict__ ids, const float* __restrict__ LI,
    float* __restrict__ partial) {
  const int t = threadIdx.x;
  const int cidx = t >> 5;          // 0..7 (col within block)
  const int sub = t & 31;
  const int j = blockIdx.x * 8 + cidx;
  float mx = -3.4e38f, E = 0.f, E2 = 0.f;
  #pragma unroll
  for (int k = 0; k < 8; ++k) {
    size_t o = (size_t)(sub + 32 * k) * B_ + j;
    mx = fmaxf(mx, cmax_p[o]);
    E += cE_p[o];
    E2 += cE2_p[o];
  }
  #pragma unroll
  for (int o = 16; o >= 1; o >>= 1) {
    mx = fmaxf(mx, __shfl_down(mx, o, 32));
    E += __shfl_down(E, o, 32);
    E2 += __shfl_down(E2, o, 32);
  }
  __shared__ float red[8];
  if (sub == 0) {
    float dg = diag[j];
    float ed = exp2f(dg * KE);
    int id = ids[j];
    float oldb = bT[id];
    float newb = fmaxf((mx - dg) * TINV, oldb);
    float sc = exp2f(-(dg * TINV + newb) * LOG2E);
    float S1 = (E - ed) * sc;
    float S2 = (E2 - dg * E) * sc;
    float g = S1 * INV_BM1;
    float sn = 0.2f * sT[id] * exp2f((oldb - newb) * LOG2E) + 0.8f * g;
    float lt = S2 / fmaxf(sn, 1e-14f) * INV_BM1;
    red[cidx] = (0.5f * LI[j] + 0.5f * lt) * (1.0f / (float)B_);
  }
  __syncthreads();
  if (t == 0) {
    float s = 0.f;
    #pragma unroll
    for (int k = 0; k < 8; ++k) s += red[k];
    partial[blockIdx.x] = s;
  }
}

// ---------------- K5: final reduce over 512 partials ----------------
__global__ void k_final2(const float* __restrict__ partial, float* __restrict__ out) {
  int t = threadIdx.x;
  float v = partial[t];
  #pragma unroll
  for (int o = 32; o >= 1; o >>= 1) v += __shfl_down(v, o);
  __shared__ float red[8];
  if ((t & 63) == 0) red[t >> 6] = v;
  __syncthreads();
  if (t == 0) {
    float s = 0.f;
    #pragma unroll
    for (int k = 0; k < 8; ++k) s += red[k];
    out[0] = s;
  }
}

extern "C" void kernel_launch(void* const* d_in, const int* in_sizes, int n_in,
                              void* d_out, int out_size, void* d_ws, size_t ws_size,
                              hipStream_t stream) {
  const float* zis = (const float*)d_in[0];
  const float* zjs = (const float*)d_in[1];
  const float* s_I = (const float*)d_in[2];
  const float* s_T = (const float*)d_in[3];
  const float* b_I = (const float*)d_in[4];
  const float* b_T = (const float*)d_in[5];
  const int*   ids = (const int*)d_in[6];

  char* ws = (char*)d_ws;
  size_t off = 0;
  auto alloc = [&](size_t bytes) -> void* {
    void* p = ws + off;
    off = (off + bytes + 255) & ~(size_t)255;
    return p;
  };
  unsigned short* Abf = (unsigned short*)alloc((size_t)B_ * D_ * 2);   // 8 MB
  unsigned short* Bbf = (unsigned short*)alloc((size_t)B_ * D_ * 2);   // 8 MB
  unsigned short* sim = (unsigned short*)alloc((size_t)B_ * B_ * 2);   // 32 MB
  float* diag   = (float*)alloc(B_ * 4);
  float* cmax_p = (float*)alloc((size_t)256 * B_ * 4);                 // 4 MB each
  float* cE_p   = (float*)alloc((size_t)256 * B_ * 4);
  float* cE2_p  = (float*)alloc((size_t)256 * B_ * 4);
  float* LI     = (float*)alloc(B_ * 4);
  float* partial = (float*)alloc(512 * 4);

  k_normalize<<<2 * B_, 256, 0, stream>>>(zis, zjs, Abf, Bbf);
  k_gemm<<<dim3(16, 16), 512, 0, stream>>>(Abf, Bbf, sim, diag);
  k_fused<<<256, 256, 0, stream>>>(sim, diag, b_I, s_I, ids, LI, cmax_p, cE_p, cE2_p);
  k_colred<<<512, 256, 0, stream>>>(diag, cmax_p, cE_p, cE2_p, b_T, s_T, ids, LI, partial);
  k_final2<<<1, 512, 0, stream>>>(partial, (float*)d_out);
}

// Round 7
// 87.456 us; speedup vs baseline: 2.3269x; 1.0446x over previous
//
#include <hip/hip_runtime.h>
#include <stdint.h>

#define B_ 4096
#define D_ 1024
#define NT 16            // K tiles (1024 / 64)
#define TINV 10.0f
#define LOG2E 1.4426950408889634f
#define KE (TINV * LOG2E)
#define INV_BM1 (1.0f / 4095.0f)

typedef __bf16 bf16x8 __attribute__((ext_vector_type(8)));
typedef float f32x4 __attribute__((ext_vector_type(4)));

__device__ __forceinline__ unsigned short f2bf(float x) {
  uint32_t b = __float_as_uint(x);
  b += 0x7FFF + ((b >> 16) & 1);   // RNE
  return (unsigned short)(b >> 16);
}
__device__ __forceinline__ float bf2f(unsigned short u) {
  return __uint_as_float(((uint32_t)u) << 16);
}

__device__ __forceinline__ void gload16(const void* g, void* l) {
  __builtin_amdgcn_global_load_lds(
      (const __attribute__((address_space(1))) uint32_t*)g,
      (__attribute__((address_space(3))) uint32_t*)l, 16, 0, 0);
}

// ---------------- K1: L2-normalize rows, emit bf16 ----------------
__global__ __launch_bounds__(256) void k_normalize(const float* __restrict__ zis,
                                                   const float* __restrict__ zjs,
                                                   unsigned short* __restrict__ Abf,
                                                   unsigned short* __restrict__ Bbf) {
  int r = blockIdx.x;
  const float* src;
  unsigned short* dst;
  if (r < B_) { src = zis + (size_t)r * D_; dst = Abf + (size_t)r * D_; }
  else        { src = zjs + (size_t)(r - B_) * D_; dst = Bbf + (size_t)(r - B_) * D_; }
  int t = threadIdx.x;
  float4 v = reinterpret_cast<const float4*>(src)[t];
  float ss = v.x*v.x + v.y*v.y + v.z*v.z + v.w*v.w;
  #pragma unroll
  for (int o = 32; o >= 1; o >>= 1) ss += __shfl_down(ss, o);
  __shared__ float red[4];
  if ((t & 63) == 0) red[t >> 6] = ss;
  __syncthreads();
  float sc = rsqrtf(red[0] + red[1] + red[2] + red[3]);
  ushort4 o4;
  o4.x = f2bf(v.x * sc); o4.y = f2bf(v.y * sc);
  o4.z = f2bf(v.z * sc); o4.w = f2bf(v.w * sc);
  reinterpret_cast<ushort4*>(dst)[t] = o4;
}

// ---------------- K2: 256x256 8-phase GEMM, relaxed sync (1 barrier/phase) ----
#define LDA(MH)                                                              \
  { _Pragma("unroll") for (int m4_ = 0; m4_ < 4; ++m4_) {                    \
      const unsigned short* p_ = &Abase[((MH)*64 + m4_*16 + fr) * 64];       \
      a[m4_][0] = *reinterpret_cast<const bf16x8*>(&p_[ce0]);                \
      a[m4_][1] = *reinterpret_cast<const bf16x8*>(&p_[ce1]); } }

#define LDB(NH)                                                              \
  { _Pragma("unroll") for (int n2_ = 0; n2_ < 2; ++n2_) {                    \
      const unsigned short* p_ = &Bbase[(bn_off + ((NH)*2+n2_)*16 + fr) * 64]; \
      b[(NH)*2+n2_][0] = *reinterpret_cast<const bf16x8*>(&p_[ce0]);         \
      b[(NH)*2+n2_][1] = *reinterpret_cast<const bf16x8*>(&p_[ce1]); } }

#define MFMAQ(MH, NH)                                                        \
  { _Pragma("unroll") for (int m4_ = 0; m4_ < 4; ++m4_) {                    \
      _Pragma("unroll") for (int n2_ = 0; n2_ < 2; ++n2_) {                  \
        acc[(MH)*4+m4_][(NH)*2+n2_] = __builtin_amdgcn_mfma_f32_16x16x32_bf16( \
            a[m4_][0], b[(NH)*2+n2_][0], acc[(MH)*4+m4_][(NH)*2+n2_], 0,0,0);  \
        acc[(MH)*4+m4_][(NH)*2+n2_] = __builtin_amdgcn_mfma_f32_16x16x32_bf16( \
            a[m4_][1], b[(NH)*2+n2_][1], acc[(MH)*4+m4_][(NH)*2+n2_], 0,0,0); } } }

#define STAGE_A(T, H)                                                        \
  { const unsigned short* g_ = Ag + (size_t)((H)*128)*D_ + (T)*64;           \
    gload16(g_ + so0, &lds[(T)&1][0][H][q0*512]);                            \
    gload16(g_ + so1, &lds[(T)&1][0][H][q1*512]); }

#define STAGE_B(T, H)                                                        \
  { const unsigned short* g_ = Bg + (size_t)((H)*128)*D_ + (T)*64;           \
    gload16(g_ + so0, &lds[(T)&1][1][H][q0*512]);                            \
    gload16(g_ + so1, &lds[(T)&1][1][H][q1*512]); }

__global__ __launch_bounds__(512, 2) void k_gemm(const unsigned short* __restrict__ A,
                                                 const unsigned short* __restrict__ B,
                                                 unsigned short* __restrict__ C,
                                                 float* __restrict__ diagp) {
  __shared__ unsigned short lds[2][2][2][8192];   // [slot][A/B][half][128*64] = 128 KB
  const int tid = threadIdx.x;
  const int wid = tid >> 6;
  const int lane = tid & 63;
  const int wm = wid >> 2;          // 0..1
  const int wn = wid & 3;           // 0..3
  const int bRow = blockIdx.y * 256;
  const int bCol = blockIdx.x * 256;
  const unsigned short* Ag = A + (size_t)bRow * D_;
  const unsigned short* Bg = B + (size_t)bCol * D_;

  // staging lane geometry (2 gload16 per wave per half-tile)
  const int q0 = wid * 2, q1 = q0 + 1;
  const int srow = q0 * 8 + (lane >> 3);            // row in half-tile (bit3 = 0)
  // pre-swizzle source col: byte bits 4,5,6 ^= row bits 1,2,3 (elems: 8,16,32)
  const int f0 = (((lane >> 4) & 1) << 3) | (((lane >> 5) & 1) << 4);
  const int scol0 = ((lane & 7) * 8) ^ f0;
  const size_t so0 = (size_t)srow * D_ + scol0;
  const size_t so1 = (size_t)(srow + 8) * D_ + (scol0 ^ 32);

  // fragment-read geometry (row bits 1,2,3 -> elem bits 3,4,5)
  const int fr = lane & 15;
  const int sx = (((lane >> 1) & 1) << 3) | (((lane >> 2) & 1) << 4) |
                 (((lane >> 3) & 1) << 5);
  const int ce0 = ((lane >> 4) * 8) ^ sx;
  const int ce1 = (((lane >> 4) * 8) + 32) ^ sx;
  const int bn_off = (wn & 1) * 64;

  f32x4 acc[8][4] = {};

  // ---- prologue: tile0 {A0,A1,B0,B1}, tile1 {B0,A0}; drain tile0 ----
  STAGE_A(0, 0); STAGE_A(0, 1); STAGE_B(0, 0); STAGE_B(0, 1);
  STAGE_B(1, 0); STAGE_A(1, 0);
  asm volatile("s_waitcnt vmcnt(4)" ::: "memory");
  __builtin_amdgcn_s_barrier();

  for (int t = 0; t < NT; ++t) {
    const int s = t & 1;
    const unsigned short* Abase = &lds[s][0][wm][0];
    const unsigned short* Bbase = &lds[s][1][wn >> 1][0];
    bf16x8 a[4][2], b[4][2];

    // P1: quadrant (mh0, nh0); stage (t+1).B1
    LDA(0); LDB(0);
    if (t + 1 < NT) { STAGE_B(t + 1, 1); }
    __builtin_amdgcn_s_setprio(1);
    MFMAQ(0, 0);
    __builtin_amdgcn_s_setprio(0);
    __builtin_amdgcn_s_barrier();

    // P2: (mh0, nh1); stage (t+1).A1
    LDB(1);
    if (t + 1 < NT) { STAGE_A(t + 1, 1); }
    __builtin_amdgcn_s_setprio(1);
    MFMAQ(0, 1);
    __builtin_amdgcn_s_setprio(0);
    __builtin_amdgcn_s_barrier();

    // P3: (mh1, nh0); stage (t+2).B0  (B0(s) reads retired by P1-end barrier)
    LDA(1);
    if (t + 2 < NT) { STAGE_B(t + 2, 0); }
    __builtin_amdgcn_s_setprio(1);
    MFMAQ(1, 0);
    __builtin_amdgcn_s_setprio(0);
    __builtin_amdgcn_s_barrier();

    // P4: (mh1, nh1); stage (t+2).A0  (A(s) reads retired by P3-end barrier)
    if (t + 2 < NT) { STAGE_A(t + 2, 0); }
    __builtin_amdgcn_s_setprio(1);
    MFMAQ(1, 1);
    __builtin_amdgcn_s_setprio(0);
    if (t < NT - 2) {
      asm volatile("s_waitcnt vmcnt(4)" ::: "memory");   // drains all t+1 halves
    } else if (t == NT - 2) {
      asm volatile("s_waitcnt vmcnt(0)" ::: "memory");
    }
    if (t < NT - 1) __builtin_amdgcn_s_barrier();
  }

  // ---- epilogue: diag (f32) + packed bf16x2 C store ----
  const int fr4 = (lane >> 4) * 4;
  #pragma unroll
  for (int m = 0; m < 8; ++m)
    #pragma unroll
    for (int n = 0; n < 4; ++n)
      #pragma unroll
      for (int q = 0; q < 4; ++q) {
        float v = acc[m][n][q];
        int rg = bRow + wm * 128 + m * 16 + fr4 + q;
        int cg = bCol + wn * 64 + n * 16 + fr;
        if (rg == cg) diagp[rg] = v;
        float p = __shfl_xor(v, 1);
        if (!(lane & 1)) {
          uint32_t u = (uint32_t)f2bf(v) | ((uint32_t)f2bf(p) << 16);
          *reinterpret_cast<uint32_t*>(&C[(size_t)rg * B_ + cg]) = u;
        }
      }
}

// ---------------- K3: fused single-read pass over bf16 sim ----------------
__global__ __launch_bounds__(256) void k_fused(const unsigned short* __restrict__ sim,
    const float* __restrict__ diag,
    const float* __restrict__ bI, const float* __restrict__ sI,
    const int* __restrict__ ids,
    float* __restrict__ LI, float* __restrict__ cmax_p,
    float* __restrict__ cE_p, float* __restrict__ cE2_p) {
  const int i0 = blockIdx.x * 16;
  const int t = threadIdx.x;
  const int w = t >> 6, lane = t & 63;
  __shared__ float rowPart[16][4][3];

  float cmax[16], cE[16], cE2[16];
  #pragma unroll
  for (int k = 0; k < 16; ++k) { cmax[k] = -3.4e38f; cE[k] = 0.f; cE2[k] = 0.f; }

  for (int r = 0; r < 16; ++r) {
    const unsigned short* sp = sim + (size_t)(i0 + r) * B_ + t * 16;
    uint4 u0 = *reinterpret_cast<const uint4*>(sp);
    uint4 u1 = *reinterpret_cast<const uint4*>(sp + 8);
    float x[16];
    x[0]  = __uint_as_float(u0.x << 16); x[1]  = __uint_as_float(u0.x & 0xffff0000u);
    x[2]  = __uint_as_float(u0.y << 16); x[3]  = __uint_as_float(u0.y & 0xffff0000u);
    x[4]  = __uint_as_float(u0.z << 16); x[5]  = __uint_as_float(u0.z & 0xffff0000u);
    x[6]  = __uint_as_float(u0.w << 16); x[7]  = __uint_as_float(u0.w & 0xffff0000u);
    x[8]  = __uint_as_float(u1.x << 16); x[9]  = __uint_as_float(u1.x & 0xffff0000u);
    x[10] = __uint_as_float(u1.y << 16); x[11] = __uint_as_float(u1.y & 0xffff0000u);
    x[12] = __uint_as_float(u1.z << 16); x[13] = __uint_as_float(u1.z & 0xffff0000u);
    x[14] = __uint_as_float(u1.w << 16); x[15] = __uint_as_float(u1.w & 0xffff0000u);
    float rmx = -3.4e38f, rE = 0.f, rE2 = 0.f;
    #pragma unroll
    for (int k = 0; k < 16; ++k) {
      float e = exp2f(x[k] * KE);
      rmx = fmaxf(rmx, x[k]);
      rE += e;
      rE2 = fmaf(e, x[k], rE2);
      cmax[k] = fmaxf(cmax[k], x[k]);
      cE[k] += e;
      cE2[k] = fmaf(e, x[k], cE2[k]);
    }
    #pragma unroll
    for (int o = 32; o >= 1; o >>= 1) {
      rmx = fmaxf(rmx, __shfl_down(rmx, o));
      rE += __shfl_down(rE, o);
      rE2 += __shfl_down(rE2, o);
    }
    if (lane == 0) { rowPart[r][w][0] = rmx; rowPart[r][w][1] = rE; rowPart[r][w][2] = rE2; }
  }
  __syncthreads();
  if (t < 16) {
    int i = i0 + t;
    float mx = fmaxf(fmaxf(rowPart[t][0][0], rowPart[t][1][0]),
                     fmaxf(rowPart[t][2][0], rowPart[t][3][0]));
    float E  = (rowPart[t][0][1] + rowPart[t][1][1]) + (rowPart[t][2][1] + rowPart[t][3][1]);
    float E2 = (rowPart[t][0][2] + rowPart[t][1][2]) + (rowPart[t][2][2] + rowPart[t][3][2]);
    float dg = diag[i];
    float ed = exp2f(dg * KE);
    int id = ids[i];
    float oldb = bI[id];
    float newb = fmaxf((mx - dg) * TINV, oldb);
    float sc = exp2f(-(dg * TINV + newb) * LOG2E);
    float S1 = (E - ed) * sc;
    float S2 = (E2 - dg * E) * sc;
    float g = S1 * INV_BM1;
    float sn = 0.2f * sI[id] * exp2f((oldb - newb) * LOG2E) + 0.8f * g;
    LI[i] = S2 / fmaxf(sn, 1e-14f) * INV_BM1;
  }
  size_t base = (size_t)blockIdx.x * B_ + t * 16;
  #pragma unroll
  for (int k = 0; k < 16; ++k) {
    cmax_p[base + k] = cmax[k];
    cE_p[base + k]   = cE[k];
    cE2_p[base + k]  = cE2[k];
  }
}

// ---------------- K4: column reduce (512 blocks, 32 threads/col) ----------------
__global__ __launch_bounds__(256) void k_colred(
    const float* __restrict__ diag,
    const float* __restrict__ cmax_p, const float* __restrict__ cE_p,
    const float* __restrict__ cE2_p,
    const float* __restrict__ bT, const float* __restrict__ sT,
    const int* __restrict__ ids, const float* __restrict__ LI,
    float* __restrict__ partial) {
  const int t = threadIdx.x;
  const int cidx = t >> 5;          // 0..7 (col within block)
  const int sub = t & 31;
  const int j = blockIdx.x * 8 + cidx;
  float mx = -3.4e38f, E = 0.f, E2 = 0.f;
  #pragma unroll
  for (int k = 0; k < 8; ++k) {
    size_t o = (size_t)(sub + 32 * k) * B_ + j;
    mx = fmaxf(mx, cmax_p[o]);
    E += cE_p[o];
    E2 += cE2_p[o];
  }
  #pragma unroll
  for (int o = 16; o >= 1; o >>= 1) {
    mx = fmaxf(mx, __shfl_down(mx, o, 32));
    E += __shfl_down(E, o, 32);
    E2 += __shfl_down(E2, o, 32);
  }
  __shared__ float red[8];
  if (sub == 0) {
    float dg = diag[j];
    float ed = exp2f(dg * KE);
    int id = ids[j];
    float oldb = bT[id];
    float newb = fmaxf((mx - dg) * TINV, oldb);
    float sc = exp2f(-(dg * TINV + newb) * LOG2E);
    float S1 = (E - ed) * sc;
    float S2 = (E2 - dg * E) * sc;
    float g = S1 * INV_BM1;
    float sn = 0.2f * sT[id] * exp2f((oldb - newb) * LOG2E) + 0.8f * g;
    float lt = S2 / fmaxf(sn, 1e-14f) * INV_BM1;
    red[cidx] = (0.5f * LI[j] + 0.5f * lt) * (1.0f / (float)B_);
  }
  __syncthreads();
  if (t == 0) {
    float s = 0.f;
    #pragma unroll
    for (int k = 0; k < 8; ++k) s += red[k];
    partial[blockIdx.x] = s;
  }
}

// ---------------- K5: final reduce over 512 partials ----------------
__global__ void k_final2(const float* __restrict__ partial, float* __restrict__ out) {
  int t = threadIdx.x;
  float v = partial[t];
  #pragma unroll
  for (int o = 32; o >= 1; o >>= 1) v += __shfl_down(v, o);
  __shared__ float red[8];
  if ((t & 63) == 0) red[t >> 6] = v;
  __syncthreads();
  if (t == 0) {
    float s = 0.f;
    #pragma unroll
    for (int k = 0; k < 8; ++k) s += red[k];
    out[0] = s;
  }
}

extern "C" void kernel_launch(void* const* d_in, const int* in_sizes, int n_in,
                              void* d_out, int out_size, void* d_ws, size_t ws_size,
                              hipStream_t stream) {
  const float* zis = (const float*)d_in[0];
  const float* zjs = (const float*)d_in[1];
  const float* s_I = (const float*)d_in[2];
  const float* s_T = (const float*)d_in[3];
  const float* b_I = (const float*)d_in[4];
  const float* b_T = (const float*)d_in[5];
  const int*   ids = (const int*)d_in[6];

  char* ws = (char*)d_ws;
  size_t off = 0;
  auto alloc = [&](size_t bytes) -> void* {
    void* p = ws + off;
    off = (off + bytes + 255) & ~(size_t)255;
    return p;
  };
  unsigned short* Abf = (unsigned short*)alloc((size_t)B_ * D_ * 2);   // 8 MB
  unsigned short* Bbf = (unsigned short*)alloc((size_t)B_ * D_ * 2);   // 8 MB
  unsigned short* sim = (unsigned short*)alloc((size_t)B_ * B_ * 2);   // 32 MB
  float* diag   = (float*)alloc(B_ * 4);
  float* cmax_p = (float*)alloc((size_t)256 * B_ * 4);                 // 4 MB each
  float* cE_p   = (float*)alloc((size_t)256 * B_ * 4);
  float* cE2_p  = (float*)alloc((size_t)256 * B_ * 4);
  float* LI     = (float*)alloc(B_ * 4);
  float* partial = (float*)alloc(512 * 4);

  k_normalize<<<2 * B_, 256, 0, stream>>>(zis, zjs, Abf, Bbf);
  k_gemm<<<dim3(16, 16), 512, 0, stream>>>(Abf, Bbf, sim, diag);
  k_fused<<<256, 256, 0, stream>>>(sim, diag, b_I, s_I, ids, LI, cmax_p, cE_p, cE2_p);
  k_colred<<<512, 256, 0, stream>>>(diag, cmax_p, cE_p, cE2_p, b_T, s_T, ids, LI, partial);
  k_final2<<<1, 512, 0, stream>>>(partial, (float*)d_out);
}